// Round 5
// baseline (523.898 us; speedup 1.0000x reference)
//
#include <hip/hip_runtime.h>
#include <hip/hip_bf16.h>

#define BATCH 1024
#define SEQ 256
#define HIDDEN 128
#define VOCAB 60
#define NT 4               // batch tiles of 16 rows per block -> 64 rows/block
#define MROWS (NT * 16)
#define ASTRIDE 136        // f16 per h row: 128 + 8 pad

typedef _Float16 f16x8 __attribute__((ext_vector_type(8)));
typedef _Float16 f16x4 __attribute__((ext_vector_type(4)));
typedef _Float16 f16x2 __attribute__((ext_vector_type(2)));
typedef float f32x4 __attribute__((ext_vector_type(4)));

__device__ __forceinline__ float fast_tanh(float x) {
    // tanh(x) = 1 - 2/(exp(2x)+1); exp(2x)=exp2(x*2*log2e). Branch-free, exact +-1 tails.
    float e = __builtin_amdgcn_exp2f(x * 2.8853900817779268f);
    return __builtin_fmaf(-2.0f, __builtin_amdgcn_rcpf(e + 1.0f), 1.0f);
}

// embW[v][i] = sum_j emb[v][j] * W_ih[i][j]  (fp32-exact input-projection table)
__global__ void rnn_prep_embw(const float* __restrict__ emb,
                              const float* __restrict__ W_ih,
                              float* __restrict__ embW) {
    const int v = blockIdx.x;
    const int i = threadIdx.x;
    __shared__ __align__(16) float e[HIDDEN];
    e[i] = emb[v * HIDDEN + i];
    __syncthreads();
    const float4* wrow = (const float4*)(W_ih + i * HIDDEN);
    const float4* e4 = (const float4*)e;
    float a0 = 0.f, a1 = 0.f, a2 = 0.f, a3 = 0.f;
#pragma unroll
    for (int j = 0; j < HIDDEN / 4; ++j) {
        float4 w = wrow[j];
        float4 h = e4[j];
        a0 += w.x * h.x; a1 += w.y * h.y; a2 += w.z * h.z; a3 += w.w * h.w;
    }
    embW[v * HIDDEN + i] = (a0 + a1) + (a2 + a3);
}

// 16 waves / 1024 threads per block, 4 independent batch tiles of 16 rows.
// wave = (tile tt = wave>>2, col-quarter wq = wave&3). Transposed recurrence
// z^T = W_hh * h^T per tile; 4 waves/SIMD give automatic latency overlap of
// 4 independent chains; one __syncthreads covers 4 tile-steps.
__global__ void __launch_bounds__(1024)
rnn_mfma(const int* __restrict__ x, const int* __restrict__ lengths,
         const float* __restrict__ embW, const float* __restrict__ W_hh,
         const float* __restrict__ W_fc, const float* __restrict__ b_fc,
         float* __restrict__ out) {
    const int tid = threadIdx.x;
    const int wave = tid >> 6;
    const int tt = wave >> 2;    // batch tile 0..3
    const int wq = wave & 3;     // col quarter 0..3
    const int lane = tid & 63;
    const int q = lane >> 4;     // 0..3
    const int r16 = lane & 15;   // batch row within tile
    const int c0 = wq * 32;      // z-col base
    const int b0 = blockIdx.x * MROWS;
    const int rloc = tt * 16 + r16;
    const int row = b0 + rloc;

    __shared__ __align__(16) _Float16 Ah[2][NT][16][ASTRIDE];  // 34816 B
    __shared__ __align__(16) _Float16 hfin[MROWS][HIDDEN];     // 16384 B
    __shared__ int lenbuf[MROWS];

    if (tid < MROWS) lenbuf[tid] = lengths[b0 + tid];
    // h_0 = 0 in both buffers.
    for (int idx = tid; idx < (int)(sizeof(Ah) / 4); idx += 1024)
        ((int*)Ah)[idx] = 0;

    // Static A-frags of W_hh: lane holds A[m=r16][k=q*8+j] per (nt,kc) tile;
    // m_global = c0 + 16*nt + r16, k = kc*32 + q*8 + j.
    f16x8 Wf[2][4];
#pragma unroll
    for (int nt = 0; nt < 2; ++nt) {
        const float* wrow = W_hh + (c0 + 16 * nt + r16) * HIDDEN + q * 8;
#pragma unroll
        for (int kc = 0; kc < 4; ++kc) {
            const float* p = wrow + kc * 32;
#pragma unroll
            for (int j = 0; j < 8; ++j) Wf[nt][kc][j] = (_Float16)p[j];
        }
    }

    __syncthreads();

    int lenmax = 0;
    for (int r = 0; r < MROWS; ++r) lenmax = max(lenmax, lenbuf[r]);  // LDS broadcast
    const int mylen = lenbuf[rloc];

    // Token / embW prefetch pipeline (tokens straight from global; L2-resident).
    const int* xrow = x + row * SEQ;
    int tok0 = xrow[0];
    const float* eb0 = embW + tok0 * HIDDEN + c0 + 4 * q;
    f32x4 pre0 = *(const f32x4*)eb0;
    f32x4 pre1 = *(const f32x4*)(eb0 + 16);
    int tokn = xrow[lenmax > 1 ? 1 : 0];

    uint2 hA = {0u, 0u}, hB = {0u, 0u};  // packed-f16 final-h capture
    int cur = 0;

    for (int t = 0; t < lenmax; ++t) {
        // B-frags (h^T) for this tile.
        const _Float16* arow = &Ah[cur][tt][r16][q * 8];
        f16x8 H0 = *(const f16x8*)(arow + 0);
        f16x8 H1 = *(const f16x8*)(arow + 32);
        f16x8 H2 = *(const f16x8*)(arow + 64);
        f16x8 H3 = *(const f16x8*)(arow + 96);

        // Prefetch: embW seed for t+1 (token fetched last iter), token for t+2.
        const float* eb = embW + tokn * HIDDEN + c0 + 4 * q;
        f32x4 pn0 = *(const f32x4*)eb;
        f32x4 pn1 = *(const f32x4*)(eb + 16);
        const int t2 = (t + 2 < lenmax) ? t + 2 : lenmax - 1;
        const int tok2 = xrow[t2];

        // 4 independent 2-deep MFMA chains (split-K).
        f32x4 a0 = pre0, a1 = pre1;
        f32x4 d0 = {0.f, 0.f, 0.f, 0.f}, d1 = {0.f, 0.f, 0.f, 0.f};
        a0 = __builtin_amdgcn_mfma_f32_16x16x32_f16(Wf[0][0], H0, a0, 0, 0, 0);
        a1 = __builtin_amdgcn_mfma_f32_16x16x32_f16(Wf[1][0], H0, a1, 0, 0, 0);
        d0 = __builtin_amdgcn_mfma_f32_16x16x32_f16(Wf[0][2], H2, d0, 0, 0, 0);
        d1 = __builtin_amdgcn_mfma_f32_16x16x32_f16(Wf[1][2], H2, d1, 0, 0, 0);
        a0 = __builtin_amdgcn_mfma_f32_16x16x32_f16(Wf[0][1], H1, a0, 0, 0, 0);
        a1 = __builtin_amdgcn_mfma_f32_16x16x32_f16(Wf[1][1], H1, a1, 0, 0, 0);
        d0 = __builtin_amdgcn_mfma_f32_16x16x32_f16(Wf[0][3], H3, d0, 0, 0, 0);
        d1 = __builtin_amdgcn_mfma_f32_16x16x32_f16(Wf[1][3], H3, d1, 0, 0, 0);
        f32x4 z0 = a0 + d0;
        f32x4 z1 = a1 + d1;

        float t00 = fast_tanh(z0[0]), t01 = fast_tanh(z0[1]);
        float t02 = fast_tanh(z0[2]), t03 = fast_tanh(z0[3]);
        float t10 = fast_tanh(z1[0]), t11 = fast_tanh(z1[1]);
        float t12 = fast_tanh(z1[2]), t13 = fast_tanh(z1[3]);

        uint2 pk0, pk1;
        pk0.x = __builtin_bit_cast(unsigned int, __builtin_amdgcn_cvt_pkrtz(t00, t01));
        pk0.y = __builtin_bit_cast(unsigned int, __builtin_amdgcn_cvt_pkrtz(t02, t03));
        pk1.x = __builtin_bit_cast(unsigned int, __builtin_amdgcn_cvt_pkrtz(t10, t11));
        pk1.y = __builtin_bit_cast(unsigned int, __builtin_amdgcn_cvt_pkrtz(t12, t13));

        if (t + 1 == mylen) { hA = pk0; hB = pk1; }

        const int nxt = cur ^ 1;
        *(uint2*)&Ah[nxt][tt][r16][c0 + 4 * q] = pk0;
        *(uint2*)&Ah[nxt][tt][r16][c0 + 16 + 4 * q] = pk1;
        __syncthreads();
        cur = nxt;
        pre0 = pn0; pre1 = pn1; tokn = tok2;
    }

    // Final h (packed f16) -> LDS, then FC epilogue.
    *(uint2*)&hfin[rloc][c0 + 4 * q] = hA;
    *(uint2*)&hfin[rloc][c0 + 16 + 4 * q] = hB;
    __syncthreads();

    const int r = tid >> 4;      // 0..63: batch row
    const int vb = tid & 15;     // 0..15
    const _Float16* hr = hfin[r];
    for (int vo = vb; vo < VOCAB; vo += 16) {
        const float4* wf = (const float4*)(W_fc + vo * HIDDEN);
        float a0 = 0.f, a1 = 0.f, a2 = 0.f, a3 = 0.f;
#pragma unroll
        for (int j = 0; j < HIDDEN / 4; ++j) {
            float4 w = wf[j];
            f16x4 hh = *(const f16x4*)(hr + 4 * j);
            a0 += w.x * (float)hh[0]; a1 += w.y * (float)hh[1];
            a2 += w.z * (float)hh[2]; a3 += w.w * (float)hh[3];
        }
        out[(b0 + r) * VOCAB + vo] = (a0 + a1) + (a2 + a3) + b_fc[vo];
    }
}

extern "C" void kernel_launch(void* const* d_in, const int* in_sizes, int n_in,
                              void* d_out, int out_size, void* d_ws, size_t ws_size,
                              hipStream_t stream) {
    const int* x = (const int*)d_in[0];          // [B, T] int32
    const int* lengths = (const int*)d_in[1];    // [B] int32
    const float* emb = (const float*)d_in[2];    // [V, H]
    const float* W_ih = (const float*)d_in[3];   // [H, H]
    const float* W_hh = (const float*)d_in[4];   // [H, H]
    const float* W_fc = (const float*)d_in[5];   // [V, H]
    const float* b_fc = (const float*)d_in[6];   // [V]
    float* out = (float*)d_out;                  // [B, V]

    float* embW = (float*)d_ws;                  // VOCAB*HIDDEN floats (30 KB)

    rnn_prep_embw<<<VOCAB, HIDDEN, 0, stream>>>(emb, W_ih, embW);
    rnn_mfma<<<BATCH / MROWS, 1024, 0, stream>>>(x, lengths, embW, W_hh, W_fc, b_fc, out);
}

// Round 7
// 437.951 us; speedup vs baseline: 1.1962x; 1.1962x over previous
//
#include <hip/hip_runtime.h>
#include <hip/hip_bf16.h>

#define BATCH 1024
#define SEQ 256
#define HIDDEN 128
#define VOCAB 60
#define WPB 8              // waves per block (each wave = independent 16-row tile)
#define HSTRIDE 136        // f16 per h row: 128 + 8 pad (272 B, 16B-aligned; dword stride 68 = 4 mod 32 rotates banks)

typedef _Float16 f16x8 __attribute__((ext_vector_type(8)));
typedef _Float16 f16x4 __attribute__((ext_vector_type(4)));
typedef float f32x4 __attribute__((ext_vector_type(4)));

__device__ __forceinline__ float fast_tanh(float x) {
    // tanh(x) = 1 - 2/(exp(2x)+1); exp(2x)=exp2(x*2*log2e). Branch-free, exact +-1 tails.
    float e = __builtin_amdgcn_exp2f(x * 2.8853900817779268f);
    return __builtin_fmaf(-2.0f, __builtin_amdgcn_rcpf(e + 1.0f), 1.0f);
}

// embW[v][i] = sum_j emb[v][j] * W_ih[i][j]  (fp32-exact input-projection table)
__global__ void rnn_prep_embw(const float* __restrict__ emb,
                              const float* __restrict__ W_ih,
                              float* __restrict__ embW) {
    const int v = blockIdx.x;
    const int i = threadIdx.x;
    __shared__ __align__(16) float e[HIDDEN];
    e[i] = emb[v * HIDDEN + i];
    __syncthreads();
    const float4* wrow = (const float4*)(W_ih + i * HIDDEN);
    const float4* e4 = (const float4*)e;
    float a0 = 0.f, a1 = 0.f, a2 = 0.f, a3 = 0.f;
#pragma unroll
    for (int j = 0; j < HIDDEN / 4; ++j) {
        float4 w = wrow[j];
        float4 h = e4[j];
        a0 += w.x * h.x; a1 += w.y * h.y; a2 += w.z * h.z; a3 += w.w * h.w;
    }
    embW[v * HIDDEN + i] = (a0 + a1) + (a2 + a3);
}

// Barrier-free wave-private RNN. Each wave owns 16 batch rows and computes the
// full z^T = W_hh * h^T (8 M-tiles x K=128 => 32 MFMAs/step). W_hh f16 A-frags
// live in 128 VGPRs; h round-trips through a wave-private LDS slice (same-wave
// DS ops complete in order => NO __syncthreads in the loop => no vmcnt/lgkmcnt
// drain, and 2 waves/SIMD overlap freely). embW seeds come from LDS (f16);
// only the token dword is global, prefetched 2 steps ahead. Per-wave early
// exit + private MFMA FC epilogue.
__global__ void __launch_bounds__(512, 2)
rnn_wave(const int* __restrict__ x, const int* __restrict__ lengths,
         const float* __restrict__ embW, const float* __restrict__ W_hh,
         const float* __restrict__ W_fc, const float* __restrict__ b_fc,
         float* __restrict__ out) {
    const int tid = threadIdx.x;
    const int wv = tid >> 6;
    const int lane = tid & 63;
    const int q = lane >> 4;     // 0..3
    const int r16 = lane & 15;   // this lane's batch row within the tile
    const int rowbase = blockIdx.x * (WPB * 16) + wv * 16;
    const int row = rowbase + r16;

    __shared__ __align__(16) _Float16 hbuf[WPB][16][HSTRIDE];  // 34816 B
    __shared__ __align__(16) _Float16 ew[VOCAB][HSTRIDE];      // 16320 B
    __shared__ int lens[WPB * 16];

    // Cooperative stage: embW (f32 global -> f16 LDS) and lengths.
    for (int idx = tid; idx < VOCAB * HIDDEN; idx += 512) {
        int v = idx >> 7, c = idx & 127;
        ew[v][c] = (_Float16)embW[idx];
    }
    if (tid < WPB * 16) lens[tid] = lengths[blockIdx.x * (WPB * 16) + tid];
    // h_0 = 0: zero the ENTIRE hbuf cooperatively (R6 bug: half-sized zero
    // left rows 8..15 as garbage -> NaN. sizeof-correct now.)
    for (int idx = tid; idx < (int)(sizeof(hbuf) / 4); idx += 512)
        ((int*)hbuf)[idx] = 0;

    // W_hh A-frags: lane(q,r16) holds A[m=r16][k=q*8+j] of M-tile mt:
    // W_hh[16*mt + r16][kc*32 + q*8 + j].  128 VGPRs, loaded once.
    f16x8 Wf[8][4];
#pragma unroll
    for (int mt = 0; mt < 8; ++mt) {
        const float* wr = W_hh + (16 * mt + r16) * HIDDEN + q * 8;
#pragma unroll
        for (int kc = 0; kc < 4; ++kc) {
            const float* p = wr + kc * 32;
#pragma unroll
            for (int j = 0; j < 8; ++j) Wf[mt][kc][j] = (_Float16)p[j];
        }
    }

    __syncthreads();  // the ONLY barrier: ew/lens/hbuf-zero visible

    const int mylen = lens[wv * 16 + r16];
    int lenmax = 0;
#pragma unroll
    for (int r = 0; r < 16; ++r) lenmax = max(lenmax, lens[wv * 16 + r]);

    // Token pipeline: tokc = token(t), tokn = token(t+1); load t+2 in-loop.
    const int* xrow = x + row * SEQ;
    int tokc = xrow[0];
    int tokn = xrow[lenmax > 1 ? 1 : 0];

    uint2 cap[8];
#pragma unroll
    for (int mt = 0; mt < 8; ++mt) cap[mt] = (uint2){0u, 0u};

    for (int t = 0; t < lenmax; ++t) {
        // Seeds from LDS (f16) for this step's token (C[m=16mt+4q+v][n=r16]).
        f16x4 sd[8];
#pragma unroll
        for (int mt = 0; mt < 8; ++mt)
            sd[mt] = *(const f16x4*)&ew[tokc][16 * mt + 4 * q];

        // h B-frags: B[k=kc*32+q*8+j][n=r16] = h[r16][k].
        const _Float16* hb = &hbuf[wv][r16][q * 8];
        f16x8 H0 = *(const f16x8*)(hb + 0);
        f16x8 H1 = *(const f16x8*)(hb + 32);
        f16x8 H2 = *(const f16x8*)(hb + 64);
        f16x8 H3 = *(const f16x8*)(hb + 96);

        // Prefetch token t+2 (global; no barrier => latency spans 2 steps).
        const int t2 = (t + 2 < lenmax) ? t + 2 : lenmax - 1;
        const int tok2 = xrow[t2];

        f32x4 C[8];
#pragma unroll
        for (int mt = 0; mt < 8; ++mt)
            C[mt] = (f32x4){(float)sd[mt][0], (float)sd[mt][1],
                            (float)sd[mt][2], (float)sd[mt][3]};

#pragma unroll
        for (int mt = 0; mt < 8; ++mt)
            C[mt] = __builtin_amdgcn_mfma_f32_16x16x32_f16(Wf[mt][0], H0, C[mt], 0, 0, 0);
#pragma unroll
        for (int mt = 0; mt < 8; ++mt)
            C[mt] = __builtin_amdgcn_mfma_f32_16x16x32_f16(Wf[mt][1], H1, C[mt], 0, 0, 0);
#pragma unroll
        for (int mt = 0; mt < 8; ++mt)
            C[mt] = __builtin_amdgcn_mfma_f32_16x16x32_f16(Wf[mt][2], H2, C[mt], 0, 0, 0);
#pragma unroll
        for (int mt = 0; mt < 8; ++mt)
            C[mt] = __builtin_amdgcn_mfma_f32_16x16x32_f16(Wf[mt][3], H3, C[mt], 0, 0, 0);

        const bool fin = (t + 1 == mylen);
#pragma unroll
        for (int mt = 0; mt < 8; ++mt) {
            float t0 = fast_tanh(C[mt][0]);
            float t1 = fast_tanh(C[mt][1]);
            float t2v = fast_tanh(C[mt][2]);
            float t3 = fast_tanh(C[mt][3]);
            uint2 pk;
            pk.x = __builtin_bit_cast(unsigned int, __builtin_amdgcn_cvt_pkrtz(t0, t1));
            pk.y = __builtin_bit_cast(unsigned int, __builtin_amdgcn_cvt_pkrtz(t2v, t3));
            if (fin) cap[mt] = pk;
            *(uint2*)&hbuf[wv][r16][16 * mt + 4 * q] = pk;  // h[r16][16mt+4q..+3]
        }
        tokc = tokn; tokn = tok2;
    }

    // ---- Wave-private FC epilogue: out = W_fc(60x128) . h^T + b_fc ----
    // Final h -> own LDS slice.
#pragma unroll
    for (int mt = 0; mt < 8; ++mt)
        *(uint2*)&hbuf[wv][r16][16 * mt + 4 * q] = cap[mt];

    // W_fc A-frags (4 M-tiles of 16 vocab rows; clamp OOB rows to 59).
    f16x8 Ff[4][4];
#pragma unroll
    for (int mtp = 0; mtp < 4; ++mtp) {
        int m = 16 * mtp + r16;
        if (m > 59) m = 59;
        const float* fr = W_fc + m * HIDDEN + q * 8;
#pragma unroll
        for (int kc = 0; kc < 4; ++kc) {
            const float* p = fr + kc * 32;
#pragma unroll
            for (int j = 0; j < 8; ++j) Ff[mtp][kc][j] = (_Float16)p[j];
        }
    }

    // Final-h B-frags (same-wave LDS: in-order DS => no barrier needed).
    const _Float16* hb = &hbuf[wv][r16][q * 8];
    f16x8 G0 = *(const f16x8*)(hb + 0);
    f16x8 G1 = *(const f16x8*)(hb + 32);
    f16x8 G2 = *(const f16x8*)(hb + 64);
    f16x8 G3 = *(const f16x8*)(hb + 96);

    f32x4 O[4];
#pragma unroll
    for (int mtp = 0; mtp < 4; ++mtp) {
        int bb = 16 * mtp + 4 * q;
        if (bb > 56) bb = 56;  // clamped group's rows are never stored
        O[mtp] = *(const f32x4*)(b_fc + bb);
    }
#pragma unroll
    for (int mtp = 0; mtp < 4; ++mtp) {
        O[mtp] = __builtin_amdgcn_mfma_f32_16x16x32_f16(Ff[mtp][0], G0, O[mtp], 0, 0, 0);
        O[mtp] = __builtin_amdgcn_mfma_f32_16x16x32_f16(Ff[mtp][1], G1, O[mtp], 0, 0, 0);
        O[mtp] = __builtin_amdgcn_mfma_f32_16x16x32_f16(Ff[mtp][2], G2, O[mtp], 0, 0, 0);
        O[mtp] = __builtin_amdgcn_mfma_f32_16x16x32_f16(Ff[mtp][3], G3, O[mtp], 0, 0, 0);
    }

    float* orow = out + row * VOCAB;
#pragma unroll
    for (int mtp = 0; mtp < 4; ++mtp) {
#pragma unroll
        for (int v = 0; v < 4; ++v) {
            int col = 16 * mtp + 4 * q + v;
            if (col < VOCAB) orow[col] = O[mtp][v];
        }
    }
}

extern "C" void kernel_launch(void* const* d_in, const int* in_sizes, int n_in,
                              void* d_out, int out_size, void* d_ws, size_t ws_size,
                              hipStream_t stream) {
    const int* x = (const int*)d_in[0];          // [B, T] int32
    const int* lengths = (const int*)d_in[1];    // [B] int32
    const float* emb = (const float*)d_in[2];    // [V, H]
    const float* W_ih = (const float*)d_in[3];   // [H, H]
    const float* W_hh = (const float*)d_in[4];   // [H, H]
    const float* W_fc = (const float*)d_in[5];   // [V, H]
    const float* b_fc = (const float*)d_in[6];   // [V]
    float* out = (float*)d_out;                  // [B, V]

    float* embW = (float*)d_ws;                  // VOCAB*HIDDEN floats (30 KB)

    rnn_prep_embw<<<VOCAB, HIDDEN, 0, stream>>>(emb, W_ih, embW);
    rnn_wave<<<BATCH / (WPB * 16), 512, 0, stream>>>(x, lengths, embW, W_hh, W_fc, b_fc, out);
}

// Round 8
// 192.063 us; speedup vs baseline: 2.7277x; 2.2802x over previous
//
#include <hip/hip_runtime.h>
#include <hip/hip_bf16.h>

#define BATCH 1024
#define SEQ 256
#define HIDDEN 128
#define VOCAB 60
#define MTILE 16
#define ASTRIDE 136        // f16 per row: 128 + 8 pad (dword stride 68 == 4 mod 32 -> rotates banks)
#define XSTRIDE (SEQ + 1)

typedef _Float16 f16x8 __attribute__((ext_vector_type(8)));
typedef _Float16 f16x4 __attribute__((ext_vector_type(4)));
typedef float f32x4 __attribute__((ext_vector_type(4)));

__device__ __forceinline__ float fast_tanh(float x) {
    // tanh(x) = 1 - 2/(exp(2x)+1); exp(2x)=exp2(x*2*log2e). Branch-free, exact +-1 tails.
    float e = __builtin_amdgcn_exp2f(x * 2.8853900817779268f);
    return __builtin_fmaf(-2.0f, __builtin_amdgcn_rcpf(e + 1.0f), 1.0f);
}

// embW[v][i] = sum_j emb[v][j] * W_ih[i][j]  (fp32-exact input-projection table)
__global__ void rnn_prep_embw(const float* __restrict__ emb,
                              const float* __restrict__ W_ih,
                              float* __restrict__ embW) {
    const int v = blockIdx.x;
    const int i = threadIdx.x;
    __shared__ __align__(16) float e[HIDDEN];
    e[i] = emb[v * HIDDEN + i];
    __syncthreads();
    const float4* wrow = (const float4*)(W_ih + i * HIDDEN);
    const float4* e4 = (const float4*)e;
    float a0 = 0.f, a1 = 0.f, a2 = 0.f, a3 = 0.f;
#pragma unroll
    for (int j = 0; j < HIDDEN / 4; ++j) {
        float4 w = wrow[j];
        float4 h = e4[j];
        a0 += w.x * h.x; a1 += w.y * h.y; a2 += w.z * h.z; a3 += w.w * h.w;
    }
    embW[v * HIDDEN + i] = (a0 + a1) + (a2 + a3);
}

// R4 structure (64 blocks x 4 waves, transposed z^T = W_hh * h^T, column split
// across waves) with ZERO global memory ops in the K-loop: embW lives in LDS
// as f16 (ew), tokens in LDS (xs). The per-step __syncthreads' vmcnt(0) drain
// is vacuous; the chain is pure LDS + MFMA + VALU.
__global__ void __launch_bounds__(256)
rnn_mfma(const int* __restrict__ x, const int* __restrict__ lengths,
         const float* __restrict__ embW, const float* __restrict__ W_hh,
         const float* __restrict__ W_fc, const float* __restrict__ b_fc,
         float* __restrict__ out) {
    const int tid = threadIdx.x;
    const int wave = tid >> 6;
    const int lane = tid & 63;
    const int q = lane >> 4;     // 0..3
    const int r16 = lane & 15;   // this lane's batch row
    const int c0 = wave * 32;    // wave's z-col base
    const int b0 = blockIdx.x * MTILE;

    __shared__ __align__(16) _Float16 Ah[2][MTILE][ASTRIDE];  // 8704 B
    __shared__ __align__(16) _Float16 ew[VOCAB][ASTRIDE];     // 16320 B
    __shared__ int xs[MTILE][XSTRIDE];                        // 16448 B
    __shared__ __align__(16) float hfin[MTILE][HIDDEN];       // 8192 B
    __shared__ int lenbuf[MTILE];

    // Stage tokens (coalesced), lengths, embW->f16 LDS; zero h (both buffers).
    for (int idx = tid; idx < MTILE * SEQ; idx += 256) {
        int r = idx >> 8, t = idx & (SEQ - 1);
        xs[r][t] = x[(b0 + r) * SEQ + t];
    }
    if (tid < MTILE) lenbuf[tid] = lengths[b0 + tid];
    for (int idx = tid; idx < VOCAB * HIDDEN; idx += 256) {
        int v = idx >> 7, c = idx & 127;
        ew[v][c] = (_Float16)embW[idx];
    }
    for (int idx = tid; idx < (int)(sizeof(Ah) / 4); idx += 256)
        ((int*)Ah)[idx] = 0;

    // Static A-frags of W_hh: lane holds A[m=r16][k=q*8+j] per (nt,kc) tile;
    // m_global = c0 + 16*nt + r16, k = kc*32 + q*8 + j.
    f16x8 Wf[2][4];
#pragma unroll
    for (int nt = 0; nt < 2; ++nt) {
        const float* wrow = W_hh + (c0 + 16 * nt + r16) * HIDDEN + q * 8;
#pragma unroll
        for (int kc = 0; kc < 4; ++kc) {
            const float* p = wrow + kc * 32;
#pragma unroll
            for (int j = 0; j < 8; ++j) Wf[nt][kc][j] = (_Float16)p[j];
        }
    }

    __syncthreads();

    const int mylen = lenbuf[r16];
    int lenmax = 0;
#pragma unroll
    for (int r = 0; r < MTILE; ++r) lenmax = max(lenmax, lenbuf[r]);

    // Seed pipeline (all LDS): seeds for step t prefetched during step t-1.
    int tok = xs[r16][0];
    f16x4 s0 = *(const f16x4*)&ew[tok][c0 + 4 * q];
    f16x4 s1 = *(const f16x4*)&ew[tok][c0 + 16 + 4 * q];

    int cur = 0;
    f32x4 hout0 = {0.f, 0.f, 0.f, 0.f}, hout1 = {0.f, 0.f, 0.f, 0.f};

    for (int t = 0; t < lenmax; ++t) {
        // h B-frags: B[k=kc*32+q*8+j][n=r16] = h[r16][k].
        const _Float16* hb = &Ah[cur][r16][q * 8];
        f16x8 H0 = *(const f16x8*)(hb + 0);
        f16x8 H1 = *(const f16x8*)(hb + 32);
        f16x8 H2 = *(const f16x8*)(hb + 64);
        f16x8 H3 = *(const f16x8*)(hb + 96);

        // Prefetch seeds for t+1 (LDS only; static tables, no hazard).
        const int tn = (t + 1 < SEQ) ? t + 1 : SEQ - 1;
        const int tok1 = xs[r16][tn];
        f16x4 sn0 = *(const f16x4*)&ew[tok1][c0 + 4 * q];
        f16x4 sn1 = *(const f16x4*)&ew[tok1][c0 + 16 + 4 * q];

        // 4 independent 2-deep MFMA chains (split-K), seeded with embW (f16->f32).
        f32x4 a0 = {(float)s0[0], (float)s0[1], (float)s0[2], (float)s0[3]};
        f32x4 a1 = {(float)s1[0], (float)s1[1], (float)s1[2], (float)s1[3]};
        f32x4 d0 = {0.f, 0.f, 0.f, 0.f}, d1 = {0.f, 0.f, 0.f, 0.f};
        a0 = __builtin_amdgcn_mfma_f32_16x16x32_f16(Wf[0][0], H0, a0, 0, 0, 0);
        a1 = __builtin_amdgcn_mfma_f32_16x16x32_f16(Wf[1][0], H0, a1, 0, 0, 0);
        d0 = __builtin_amdgcn_mfma_f32_16x16x32_f16(Wf[0][2], H2, d0, 0, 0, 0);
        d1 = __builtin_amdgcn_mfma_f32_16x16x32_f16(Wf[1][2], H2, d1, 0, 0, 0);
        a0 = __builtin_amdgcn_mfma_f32_16x16x32_f16(Wf[0][1], H1, a0, 0, 0, 0);
        a1 = __builtin_amdgcn_mfma_f32_16x16x32_f16(Wf[1][1], H1, a1, 0, 0, 0);
        d0 = __builtin_amdgcn_mfma_f32_16x16x32_f16(Wf[0][3], H3, d0, 0, 0, 0);
        d1 = __builtin_amdgcn_mfma_f32_16x16x32_f16(Wf[1][3], H3, d1, 0, 0, 0);
        f32x4 z0 = a0 + d0;
        f32x4 z1 = a1 + d1;

        f32x4 th0, th1;
#pragma unroll
        for (int v = 0; v < 4; ++v) {
            th0[v] = fast_tanh(z0[v]);
            th1[v] = fast_tanh(z1[v]);
        }
        if (t + 1 == mylen) { hout0 = th0; hout1 = th1; }

        uint2 pk0, pk1;
        pk0.x = __builtin_bit_cast(unsigned int, __builtin_amdgcn_cvt_pkrtz(th0[0], th0[1]));
        pk0.y = __builtin_bit_cast(unsigned int, __builtin_amdgcn_cvt_pkrtz(th0[2], th0[3]));
        pk1.x = __builtin_bit_cast(unsigned int, __builtin_amdgcn_cvt_pkrtz(th1[0], th1[1]));
        pk1.y = __builtin_bit_cast(unsigned int, __builtin_amdgcn_cvt_pkrtz(th1[2], th1[3]));

        const int nxt = cur ^ 1;
        *(uint2*)&Ah[nxt][r16][c0 + 4 * q] = pk0;
        *(uint2*)&Ah[nxt][r16][c0 + 16 + 4 * q] = pk1;
        __syncthreads();
        cur = nxt;
        s0 = sn0; s1 = sn1;
    }

    // Final h (fp32) -> LDS, then FC epilogue.
#pragma unroll
    for (int v = 0; v < 4; ++v) {
        hfin[r16][c0 + 4 * q + v] = hout0[v];
        hfin[r16][c0 + 16 + 4 * q + v] = hout1[v];
    }
    __syncthreads();

    const int r = tid >> 4;       // 0..15
    const int vbase = tid & 15;   // 0..15
    const float4* hv = (const float4*)hfin[r];
    for (int vo = vbase; vo < VOCAB; vo += 16) {
        const float4* wf = (const float4*)(W_fc + vo * HIDDEN);
        float a0 = 0.f, a1 = 0.f, a2 = 0.f, a3 = 0.f;
#pragma unroll
        for (int j = 0; j < HIDDEN / 4; ++j) {
            float4 a = hv[j];
            float4 w = wf[j];
            a0 += a.x * w.x; a1 += a.y * w.y; a2 += a.z * w.z; a3 += a.w * w.w;
        }
        out[(b0 + r) * VOCAB + vo] = (a0 + a1) + (a2 + a3) + b_fc[vo];
    }
}

extern "C" void kernel_launch(void* const* d_in, const int* in_sizes, int n_in,
                              void* d_out, int out_size, void* d_ws, size_t ws_size,
                              hipStream_t stream) {
    const int* x = (const int*)d_in[0];          // [B, T] int32
    const int* lengths = (const int*)d_in[1];    // [B] int32
    const float* emb = (const float*)d_in[2];    // [V, H]
    const float* W_ih = (const float*)d_in[3];   // [H, H]
    const float* W_hh = (const float*)d_in[4];   // [H, H]
    const float* W_fc = (const float*)d_in[5];   // [V, H]
    const float* b_fc = (const float*)d_in[6];   // [V]
    float* out = (float*)d_out;                  // [B, V]

    float* embW = (float*)d_ws;                  // VOCAB*HIDDEN floats (30 KB)

    rnn_prep_embw<<<VOCAB, HIDDEN, 0, stream>>>(emb, W_ih, embW);
    rnn_mfma<<<BATCH / MTILE, 256, 0, stream>>>(x, lengths, embW, W_hh, W_fc, b_fc, out);
}

// Round 9
// 175.348 us; speedup vs baseline: 2.9878x; 1.0953x over previous
//
#include <hip/hip_runtime.h>
#include <hip/hip_bf16.h>

#define BATCH 1024
#define SEQ 256
#define HIDDEN 128
#define VOCAB 60
#define MTILE 16
#define ASTRIDE 136        // f16 per row: 128 + 8 pad (dword stride 68 == 4 mod 32 -> rotates banks)
#define XSTRIDE (SEQ + 1)

typedef _Float16 f16x8 __attribute__((ext_vector_type(8)));
typedef _Float16 f16x4 __attribute__((ext_vector_type(4)));
typedef float f32x4 __attribute__((ext_vector_type(4)));

__device__ __forceinline__ float fast_tanh(float x) {
    // tanh(x) = 1 - 2/(exp(2x)+1); exp(2x)=exp2(x*2*log2e). Branch-free, exact +-1 tails.
    float e = __builtin_amdgcn_exp2f(x * 2.8853900817779268f);
    return __builtin_fmaf(-2.0f, __builtin_amdgcn_rcpf(e + 1.0f), 1.0f);
}

// embW[v][i] = sum_j emb[v][j] * W_ih[i][j]  (fp32-exact input-projection table)
__global__ void rnn_prep_embw(const float* __restrict__ emb,
                              const float* __restrict__ W_ih,
                              float* __restrict__ embW) {
    const int v = blockIdx.x;
    const int i = threadIdx.x;
    __shared__ __align__(16) float e[HIDDEN];
    e[i] = emb[v * HIDDEN + i];
    __syncthreads();
    const float4* wrow = (const float4*)(W_ih + i * HIDDEN);
    const float4* e4 = (const float4*)e;
    float a0 = 0.f, a1 = 0.f, a2 = 0.f, a3 = 0.f;
#pragma unroll
    for (int j = 0; j < HIDDEN / 4; ++j) {
        float4 w = wrow[j];
        float4 h = e4[j];
        a0 += w.x * h.x; a1 += w.y * h.y; a2 += w.z * h.z; a3 += w.w * h.w;
    }
    embW[v * HIDDEN + i] = (a0 + a1) + (a2 + a3);
}

// 64 blocks x 8 waves (512 thr). Transposed recurrence z^T = W_hh * h^T; wave w
// owns z-cols [16w, 16w+16) -> 2 waves/SIMD so two independent instruction
// streams co-schedule: one wave's ds_read/tanh latency is filled by the other.
// Per lane per step: 1 tok b32 + 1 seed b64 (both LDS, prefetched t+1),
// 4 ds_read_b128 h-frags, 4 MFMA (2 indep 2-chains), 4 tanh, 1 ds_write_b64,
// 1 barrier. Zero global ops in the loop.
__global__ void __launch_bounds__(512)
rnn_mfma(const int* __restrict__ x, const int* __restrict__ lengths,
         const float* __restrict__ embW, const float* __restrict__ W_hh,
         const float* __restrict__ W_fc, const float* __restrict__ b_fc,
         float* __restrict__ out) {
    const int tid = threadIdx.x;
    const int wave = tid >> 6;   // 0..7
    const int lane = tid & 63;
    const int q = lane >> 4;     // 0..3
    const int r16 = lane & 15;   // this lane's batch row
    const int c0 = wave * 16;    // wave's z-col base (16 cols)
    const int b0 = blockIdx.x * MTILE;

    __shared__ __align__(16) _Float16 Ah[2][MTILE][ASTRIDE];  // 8704 B
    __shared__ __align__(16) _Float16 ew[VOCAB][ASTRIDE];     // 16320 B
    __shared__ int xs[MTILE][XSTRIDE];                        // 16448 B
    __shared__ __align__(16) float hfin[MTILE][HIDDEN];       // 8192 B
    __shared__ int lenbuf[MTILE];

    // Stage tokens (coalesced), lengths, embW->f16 LDS; zero h (both buffers).
    for (int idx = tid; idx < MTILE * SEQ; idx += 512) {
        int r = idx >> 8, t = idx & (SEQ - 1);
        xs[r][t] = x[(b0 + r) * SEQ + t];
    }
    if (tid < MTILE) lenbuf[tid] = lengths[b0 + tid];
    for (int idx = tid; idx < VOCAB * HIDDEN; idx += 512) {
        int v = idx >> 7, c = idx & 127;
        ew[v][c] = (_Float16)embW[idx];
    }
    for (int idx = tid; idx < (int)(sizeof(Ah) / 4); idx += 512)
        ((int*)Ah)[idx] = 0;

    // Static A-frags of W_hh for this wave's 16-col M-tile:
    // A[m=r16][k=kc*32+q*8+j] = W_hh[c0 + r16][kc*32 + q*8 + j]. 16 VGPRs.
    f16x8 Wf[4];
    {
        const float* wrow = W_hh + (c0 + r16) * HIDDEN + q * 8;
#pragma unroll
        for (int kc = 0; kc < 4; ++kc) {
            const float* p = wrow + kc * 32;
#pragma unroll
            for (int j = 0; j < 8; ++j) Wf[kc][j] = (_Float16)p[j];
        }
    }

    __syncthreads();

    const int mylen = lenbuf[r16];
    int lenmax = 0;
#pragma unroll
    for (int r = 0; r < MTILE; ++r) lenmax = max(lenmax, lenbuf[r]);

    // Seed pipeline (all LDS): seed for step t prefetched during step t-1.
    int tok = xs[r16][0];
    f16x4 sd = *(const f16x4*)&ew[tok][c0 + 4 * q];

    int cur = 0;
    uint2 cap = {0u, 0u};

    for (int t = 0; t < lenmax; ++t) {
        // h B-frags: B[k=kc*32+q*8+j][n=r16] = h[r16][k].
        const _Float16* hb = &Ah[cur][r16][q * 8];
        f16x8 H0 = *(const f16x8*)(hb + 0);
        f16x8 H1 = *(const f16x8*)(hb + 32);
        f16x8 H2 = *(const f16x8*)(hb + 64);
        f16x8 H3 = *(const f16x8*)(hb + 96);

        // Prefetch seed for t+1 (token read then table read; both LDS).
        const int tn = (t + 1 < SEQ) ? t + 1 : SEQ - 1;
        const int tok1 = xs[r16][tn];
        f16x4 sn = *(const f16x4*)&ew[tok1][c0 + 4 * q];

        // 2 independent 2-deep MFMA chains, seeded with embW (f16->f32).
        f32x4 a = {(float)sd[0], (float)sd[1], (float)sd[2], (float)sd[3]};
        f32x4 d = {0.f, 0.f, 0.f, 0.f};
        a = __builtin_amdgcn_mfma_f32_16x16x32_f16(Wf[0], H0, a, 0, 0, 0);
        d = __builtin_amdgcn_mfma_f32_16x16x32_f16(Wf[2], H2, d, 0, 0, 0);
        a = __builtin_amdgcn_mfma_f32_16x16x32_f16(Wf[1], H1, a, 0, 0, 0);
        d = __builtin_amdgcn_mfma_f32_16x16x32_f16(Wf[3], H3, d, 0, 0, 0);
        f32x4 z = a + d;

        float t0 = fast_tanh(z[0]);
        float t1 = fast_tanh(z[1]);
        float t2 = fast_tanh(z[2]);
        float t3 = fast_tanh(z[3]);

        uint2 pk;
        pk.x = __builtin_bit_cast(unsigned int, __builtin_amdgcn_cvt_pkrtz(t0, t1));
        pk.y = __builtin_bit_cast(unsigned int, __builtin_amdgcn_cvt_pkrtz(t2, t3));
        if (t + 1 == mylen) cap = pk;

        const int nxt = cur ^ 1;
        *(uint2*)&Ah[nxt][r16][c0 + 4 * q] = pk;
        __syncthreads();
        cur = nxt;
        sd = sn;
    }

    // Final h (fp32) -> LDS, then FC epilogue.
    {
        f16x4 hc = __builtin_bit_cast(f16x4, cap);
#pragma unroll
        for (int v = 0; v < 4; ++v)
            hfin[r16][c0 + 4 * q + v] = (float)hc[v];
    }
    __syncthreads();

    // FC: 512 threads, 16 rows x 32 vocab-slots.
    const int r = tid >> 5;       // 0..15
    const int vb = tid & 31;      // 0..31
    const float4* hv = (const float4*)hfin[r];
    for (int vo = vb; vo < VOCAB; vo += 32) {
        const float4* wf = (const float4*)(W_fc + vo * HIDDEN);
        float a0 = 0.f, a1 = 0.f, a2 = 0.f, a3 = 0.f;
#pragma unroll
        for (int j = 0; j < HIDDEN / 4; ++j) {
            float4 a = hv[j];
            float4 w = wf[j];
            a0 += a.x * w.x; a1 += a.y * w.y; a2 += a.z * w.z; a3 += a.w * w.w;
        }
        out[(b0 + r) * VOCAB + vo] = (a0 + a1) + (a2 + a3) + b_fc[vo];
    }
}

extern "C" void kernel_launch(void* const* d_in, const int* in_sizes, int n_in,
                              void* d_out, int out_size, void* d_ws, size_t ws_size,
                              hipStream_t stream) {
    const int* x = (const int*)d_in[0];          // [B, T] int32
    const int* lengths = (const int*)d_in[1];    // [B] int32
    const float* emb = (const float*)d_in[2];    // [V, H]
    const float* W_ih = (const float*)d_in[3];   // [H, H]
    const float* W_hh = (const float*)d_in[4];   // [H, H]
    const float* W_fc = (const float*)d_in[5];   // [V, H]
    const float* b_fc = (const float*)d_in[6];   // [V]
    float* out = (float*)d_out;                  // [B, V]

    float* embW = (float*)d_ws;                  // VOCAB*HIDDEN floats (30 KB)

    rnn_prep_embw<<<VOCAB, HIDDEN, 0, stream>>>(emb, W_ih, embW);
    rnn_mfma<<<BATCH / MTILE, 512, 0, stream>>>(x, lengths, embW, W_hh, W_fc, b_fc, out);
}